// Round 1
// 778.131 us; speedup vs baseline: 1.1274x; 1.1274x over previous
//
#include <hip/hip_runtime.h>
#include <hip/hip_fp16.h>
#include <stdint.h>
#include <stddef.h>

typedef _Float16 f16;
typedef __attribute__((ext_vector_type(4))) _Float16 f16x4;
typedef __attribute__((ext_vector_type(8))) _Float16 f16x8;
typedef __attribute__((ext_vector_type(4))) float f32x4;

// async global->LDS, 16B per lane. LDS dest is wave-uniform base + lane*16.
__device__ __forceinline__ void gld_lds16(const void* g, void* l) {
  __builtin_amdgcn_global_load_lds((const __attribute__((address_space(1))) void*)g,
                                   (__attribute__((address_space(3))) void*)l, 16, 0, 0);
}

template <int N>
__device__ __forceinline__ void wait_vmcnt() {
  if constexpr (N == 0) __asm__ volatile("s_waitcnt vmcnt(0)" ::: "memory");
  else if constexpr (N == 6) __asm__ volatile("s_waitcnt vmcnt(6)" ::: "memory");
}

// ---------------- fused cast f32 -> f16 for all 5 tensors ----------------
__global__ void cast_all(const float* __restrict__ x, const float* __restrict__ wq,
                         const float* __restrict__ wk, const float* __restrict__ wv,
                         const float* __restrict__ wo, f16* __restrict__ xh,
                         f16* __restrict__ wqh, f16* __restrict__ wkh,
                         f16* __restrict__ wvh, f16* __restrict__ woh) {
  int i = blockIdx.x * blockDim.x + threadIdx.x;
  const float* in;
  f16* out;
  int j = i;
  if (j < 4194304) { in = x; out = xh; }
  else if ((j -= 4194304) < 4194304) { in = wq; out = wqh; }
  else if ((j -= 4194304) < 1048576) { in = wk; out = wkh; }
  else if ((j -= 1048576) < 1048576) { in = wv; out = wvh; }
  else { j -= 1048576; in = wo; out = woh; }
  float4 v = ((const float4*)in)[j];
  f16x4 h;
  h[0] = (f16)v.x; h[1] = (f16)v.y; h[2] = (f16)v.z; h[3] = (f16)v.w;
  *(f16x4*)(out + (size_t)j * 4) = h;
}

// ---------------- GEMM core: C(256x128) = A(256xK) * B(128xK)^T, K=4096 ----------------
// Deep-pipelined schedule (T2+T3+T4+T5):
//   - 8 waves (2Mx... wr in 0..3 owns 64 rows, wc in 0..1 owns 64 cols; per-wave 64x64,
//     acc = 4x4 frags of 16x16, MFMA = 16x16x32_f16).
//   - BK=64 K-tiles, 2 phases/tile (ks=0, ks=1), 16 MFMA per phase, raw s_barrier only
//     (no __syncthreads -> no implicit vmcnt(0) drain).
//   - LDS ring of 3 buffers (A 32KB + B 16KB each = 144 KiB total). During tile t, all
//     6 global_load_lds for tile t+2 are issued in phase 2, then s_waitcnt vmcnt(6):
//     leaves exactly tile t+2's loads in flight, guarantees tile t+1 landed (checked one
//     barrier before its first read; ~2 tiles of flight hides HBM latency). Overwrite
//     safety: buffer (t+2)%3 was last read at tile t-1 phase 2; every wave has passed
//     that read's lgkmcnt (forced by its own MFMA) before any wave can issue the stage
//     (two barriers in between).
//   - 3-bit XOR granule swizzle: physical granule = logical ^ (row&7); a fragment
//     ds_read_b128 then hits each 16B bank-group with 2 lanes (2-way = free).
__device__ __forceinline__ void gemm_core256(const f16* __restrict__ Ab,
                                             const f16* __restrict__ Bb,
                                             f16* __restrict__ lds,
                                             f32x4 acc[4][4]) {
  const int tid = threadIdx.x, ln = tid & 63, wv = tid >> 6;
  const int wr = wv >> 1, wc = wv & 1;
  const int c16 = ln & 15, quad = ln >> 4;
#pragma unroll
  for (int mi = 0; mi < 4; ++mi)
#pragma unroll
    for (int ni = 0; ni < 4; ++ni) {
      f32x4 z = {0.f, 0.f, 0.f, 0.f};
      acc[mi][ni] = z;
    }
  // staging map: thread stages physical granule P; invert swizzle on the global source.
  int srA[4], scA[4];
#pragma unroll
  for (int u = 0; u < 4; ++u) {
    int P = u * 512 + wv * 64 + ln;
    int pr = P >> 3;
    srA[u] = pr;
    scA[u] = ((P & 7) ^ (pr & 7)) * 8;
  }
  // fragment read offsets: row*64 + (granule ^ (row&7))*8 ; row&7 == c16&7.
  int offA[4], offB[4];
#pragma unroll
  for (int i = 0; i < 4; ++i) {
    offA[i] = (wr * 64 + i * 16 + c16) * 64;
    offB[i] = (wc * 64 + i * 16 + c16) * 64;
  }
  const int gk0 = ((0 + quad) ^ (c16 & 7)) * 8;
  const int gk1 = ((4 + quad) ^ (c16 & 7)) * 8;

#define STAGE(BUF, K0)                                                        \
  {                                                                           \
    _Pragma("unroll") for (int u = 0; u < 4; ++u) {                           \
      gld_lds16(Ab + (size_t)srA[u] * 4096 + (K0) + scA[u],                   \
                lds + (BUF) + (u * 512 + wv * 64) * 8);                       \
    }                                                                         \
    _Pragma("unroll") for (int u = 0; u < 2; ++u) {                           \
      gld_lds16(Bb + (size_t)srA[u] * 4096 + (K0) + scA[u],                   \
                lds + (BUF) + 16384 + (u * 512 + wv * 64) * 8);               \
    }                                                                         \
  }

#define READS(BUF, GK)                                                        \
  _Pragma("unroll") for (int i = 0; i < 4; ++i) {                             \
    af[i] = *(const f16x8*)&lds[(BUF) + offA[i] + (GK)];                      \
  }                                                                           \
  _Pragma("unroll") for (int i = 0; i < 4; ++i) {                             \
    bf[i] = *(const f16x8*)&lds[(BUF) + 16384 + offB[i] + (GK)];              \
  }

#define BARRIER()                                                             \
  __builtin_amdgcn_sched_barrier(0);                                          \
  __builtin_amdgcn_s_barrier();                                               \
  __builtin_amdgcn_sched_barrier(0);

#define MFMA16()                                                              \
  __builtin_amdgcn_s_setprio(1);                                              \
  _Pragma("unroll") for (int mi = 0; mi < 4; ++mi) {                          \
    _Pragma("unroll") for (int ni = 0; ni < 4; ++ni) {                        \
      acc[mi][ni] = __builtin_amdgcn_mfma_f32_16x16x32_f16(                   \
          af[mi], bf[ni], acc[mi][ni], 0, 0, 0);                              \
    }                                                                         \
  }                                                                           \
  __builtin_amdgcn_s_setprio(0);

  int b0 = 0, b1 = 24576, b2 = 49152;  // f16 offsets of ring buffers
  f16x8 af[4], bf[4];

  // prologue: tiles 0 and 1 in flight; wait tile 0 (tile 1's 6 loads stay outstanding)
  STAGE(b0, 0);
  STAGE(b1, 64);
  wait_vmcnt<6>();
  BARRIER();

#pragma unroll 1
  for (int t = 0; t < 62; ++t) {
    // phase 1 (ks=0)
    READS(b0, gk0);
    BARRIER();
    MFMA16();
    // phase 2 (ks=1): stage tile t+2, counted wait covers tile t+1
    READS(b0, gk1);
    STAGE(b2, (t + 2) * 64);
    wait_vmcnt<6>();
    BARRIER();
    MFMA16();
    int tmp = b0; b0 = b1; b1 = b2; b2 = tmp;
  }
  // t = 62: nothing left to stage; drain for tile 63
  READS(b0, gk0);
  BARRIER();
  MFMA16();
  READS(b0, gk1);
  wait_vmcnt<0>();
  BARRIER();
  MFMA16();
  // t = 63
  READS(b1, gk0);
  MFMA16();
  READS(b1, gk1);
  MFMA16();

#undef STAGE
#undef READS
#undef BARRIER
#undef MFMA16
}

// ---------------- fused QKV projection ----------------
// 768 blocks (XCD-swizzled): bx<32 -> Q cols, bx<40 -> K cols, else V (transposed).
__global__ __launch_bounds__(512, 2) void gemm_qkv(
    const f16* __restrict__ xh, const f16* __restrict__ wqh,
    const f16* __restrict__ wkh, const f16* __restrict__ wvh,
    f16* __restrict__ qh, f16* __restrict__ kh, f16* __restrict__ vt) {
  __shared__ __align__(16) f16 lds[73728];  // 144 KiB: ring of 3 x (A 32K + B 16K)
  const int id = blockIdx.x;
  const int swz = (id & 7) * 96 + (id >> 3);  // 768 = 8 XCD * 96 (bijective)
  const int bx = swz % 48, by = swz / 48;     // bx-major: A strip (2MB) stays in L2
  const f16* Bb;
  if (bx < 32)      Bb = wqh + (size_t)bx * 128 * 4096;
  else if (bx < 40) Bb = wkh + (size_t)(bx - 32) * 128 * 4096;
  else              Bb = wvh + (size_t)(bx - 40) * 128 * 4096;
  f32x4 acc[4][4];
  gemm_core256(xh + (size_t)by * 256 * 4096, Bb, lds, acc);
  const int tid = threadIdx.x, ln = tid & 63, wv = tid >> 6;
  const int wr = wv >> 1, wc = wv & 1;
  const int c16 = ln & 15, quad = ln >> 4;
  // C/D layout (16x16): col = c16, row = quad*4 + r
#pragma unroll
  for (int mi = 0; mi < 4; ++mi)
#pragma unroll
    for (int ni = 0; ni < 4; ++ni) {
      int colb = wc * 64 + ni * 16 + c16;                // col within the 128-block
      int m0 = by * 256 + wr * 64 + mi * 16 + quad * 4;  // token of reg 0
      if (bx < 32) {
#pragma unroll
        for (int r = 0; r < 4; ++r)
          qh[(size_t)(m0 + r) * 4096 + bx * 128 + colb] = (f16)acc[mi][ni][r];
      } else if (bx < 40) {
#pragma unroll
        for (int r = 0; r < 4; ++r)
          kh[(size_t)(m0 + r) * 1024 + (bx - 32) * 128 + colb] = (f16)acc[mi][ni][r];
      } else {
        f16x4 v4;
#pragma unroll
        for (int r = 0; r < 4; ++r) v4[r] = (f16)acc[mi][ni][r];
        int n2 = (bx - 40) * 128 + colb;
        int kv = n2 >> 7, d = n2 & 127;
        int bbv = m0 >> 11, sl = m0 & 2047;  // 4 consecutive tokens, same batch (m0%4==0)
        *(f16x4*)&vt[(((size_t)bbv * 8 + kv) * 128 + d) * 2048 + sl] = v4;
      }
    }
}

// ---------------- RoPE in-place on Q and K (16B per thread) ----------------
__global__ void rope_qk(f16* __restrict__ qh, f16* __restrict__ kh,
                        const float* __restrict__ fc, const float* __restrict__ fs) {
  int i = blockIdx.x * blockDim.x + threadIdx.x;  // granule = 8 f16 = 4 rot pairs
  const int QG = 4096 * 32 * 16;
  f16* ptr;
  int sl, p0;
  if (i < QG) {
    int g = i & 15, head = (i >> 4) & 31, tok = i >> 9;
    sl = tok & 2047; p0 = g * 4;
    ptr = qh + (size_t)tok * 4096 + head * 128 + g * 8;
  } else {
    int j = i - QG;
    int g = j & 15, head = (j >> 4) & 7, tok = j >> 7;
    sl = tok & 2047; p0 = g * 4;
    ptr = kh + (size_t)tok * 1024 + head * 128 + g * 8;
  }
  f16x8 v = *(f16x8*)ptr;
  float4 c = *(const float4*)&fc[sl * 64 + p0];
  float4 s = *(const float4*)&fs[sl * 64 + p0];
  f16x8 o;
  o[0] = (f16)((float)v[0] * c.x - (float)v[1] * s.x);
  o[1] = (f16)((float)v[0] * s.x + (float)v[1] * c.x);
  o[2] = (f16)((float)v[2] * c.y - (float)v[3] * s.y);
  o[3] = (f16)((float)v[2] * s.y + (float)v[3] * c.y);
  o[4] = (f16)((float)v[4] * c.z - (float)v[5] * s.z);
  o[5] = (f16)((float)v[4] * s.z + (float)v[5] * c.z);
  o[6] = (f16)((float)v[6] * c.w - (float)v[7] * s.w);
  o[7] = (f16)((float)v[6] * s.w + (float)v[7] * c.w);
  *(f16x8*)ptr = o;
}

// ---------------- causal GQA flash attention (transposed S/O formulation) ----------------
// grid (32 qtiles, 32 heads, 2 batch), 4 waves, each wave a 16-query strip (q = lane&15).
// S^T = K Q^T  (lane owns query col q=c16 -> in-lane softmax), O^T = V^T P^T.
__global__ __launch_bounds__(256, 4) void attn(
    const f16* __restrict__ qh, const f16* __restrict__ kh,
    const f16* __restrict__ vt, f16* __restrict__ ao) {
  __shared__ __align__(16) f16 Kl[64 * 128];   // [s][d], granule-swizzled g^(s&15)
  __shared__ __align__(16) f16 Vl[128 * 64];   // [d][s], granule-swizzled g^(d&7)
  __shared__ __align__(16) f16 Pl[4][16 * 64]; // per-wave P [q][k], granule-swizzled g^(q&7)
  const int qt = 31 - blockIdx.x;  // longest blocks dispatch first
  const int h = blockIdx.y, bb = blockIdx.z;
  const int kvh = h >> 2;
  const int tid = threadIdx.x, ln = tid & 63, wv = tid >> 6;
  const int quad = ln >> 4, c16 = ln & 15;

  // Q fragment (A/B layout identical): lane holds Q[q=strip row c16][d = ks*32+quad*8+j]
  f16x8 Qf[4];
  {
    size_t qbase = ((size_t)(bb * 2048 + qt * 64 + wv * 16 + c16)) * 4096 + h * 128;
#pragma unroll
    for (int ks = 0; ks < 4; ++ks)
      Qf[ks] = *(const f16x8*)&qh[qbase + ks * 32 + quad * 8];
  }
  float m_run = -INFINITY, l_run = 0.f;
  f32x4 Ot[8];  // O^T tiles over d; lane col = q
#pragma unroll
  for (int n = 0; n < 8; ++n) { f32x4 z = {0.f, 0.f, 0.f, 0.f}; Ot[n] = z; }
  const float scale = 0.08838834764831843f;  // 1/sqrt(128)
  const int qg = qt * 64 + wv * 16 + c16;    // this lane's global query index
  const int swp = ((quad ^ (c16 & 7)) * 8);         // Pl read swizzle, ks=0
  const int swp1 = (((4 + quad) ^ (c16 & 7)) * 8);  // ks=1

  for (int t = 0; t <= qt; ++t) {
    // stage K tile [64][128] and V^T tile [128][64] (swizzled), 4+4 chunks per wave
#pragma unroll
    for (int c = 0; c < 4; ++c) {
      int chunk = wv * 4 + c;
      int krow = chunk * 4 + (ln >> 4);
      int kg = (ln & 15) ^ (krow & 15);
      gld_lds16(&kh[((size_t)(bb * 2048 + t * 64 + krow)) * 1024 + kvh * 128 + kg * 8],
                &Kl[chunk * 512]);
    }
#pragma unroll
    for (int c = 0; c < 4; ++c) {
      int chunk = wv * 4 + c;
      int vrow = chunk * 8 + (ln >> 3);
      int vg = (ln & 7) ^ (vrow & 7);
      gld_lds16(&vt[(((size_t)bb * 8 + kvh) * 128 + vrow) * 2048 + t * 64 + vg * 8],
                &Vl[chunk * 512]);
    }
    __syncthreads();

    // S^T(64x16 per wave): Sa[tn] = K-tile(tn) x Q^T; D[k'=quad*4+r][q=c16]
    f32x4 Sa[4];
#pragma unroll
    for (int tn = 0; tn < 4; ++tn) {
      f32x4 z = {0.f, 0.f, 0.f, 0.f};
      Sa[tn] = z;
#pragma unroll
      for (int ks = 0; ks < 4; ++ks) {
        f16x8 kf = *(const f16x8*)&Kl[(tn * 16 + c16) * 128 + (((ks * 4 + quad) ^ c16) * 8)];
        Sa[tn] = __builtin_amdgcn_mfma_f32_16x16x32_f16(kf, Qf[ks], Sa[tn], 0, 0, 0);
      }
    }

    // scale + causal mask (diagonal tile only)
#pragma unroll
    for (int tn = 0; tn < 4; ++tn)
#pragma unroll
      for (int r = 0; r < 4; ++r) Sa[tn][r] *= scale;
    if (t == qt) {
#pragma unroll
      for (int tn = 0; tn < 4; ++tn) {
        int kbase = t * 64 + tn * 16 + quad * 4;
#pragma unroll
        for (int r = 0; r < 4; ++r)
          if (kbase + r > qg) Sa[tn][r] = -INFINITY;
      }
    }

    // online softmax: per-lane (one q per lane), 2 shuffles per reduction
    float mm = -INFINITY;
#pragma unroll
    for (int tn = 0; tn < 4; ++tn)
#pragma unroll
      for (int r = 0; r < 4; ++r) mm = fmaxf(mm, Sa[tn][r]);
    mm = fmaxf(mm, __shfl_xor(mm, 16, 64));
    mm = fmaxf(mm, __shfl_xor(mm, 32, 64));
    float mn = fmaxf(m_run, mm);
    float alpha = __expf(m_run - mn);
    m_run = mn;
    float rsum = 0.f;
#pragma unroll
    for (int tn = 0; tn < 4; ++tn)
#pragma unroll
      for (int r = 0; r < 4; ++r) {
        float p = __expf(Sa[tn][r] - mn);
        Sa[tn][r] = p;
        rsum += p;
      }
    rsum += __shfl_xor(rsum, 16, 64);
    rsum += __shfl_xor(rsum, 32, 64);
    l_run = l_run * alpha + rsum;

    // P^T (C-layout) -> Pl[q][k] (8B packed, swizzled)
#pragma unroll
    for (int tn = 0; tn < 4; ++tn) {
      f16x4 pk;
#pragma unroll
      for (int r = 0; r < 4; ++r) pk[r] = (f16)Sa[tn][r];
      int g = tn * 2 + (quad >> 1);
      *(f16x4*)&Pl[wv][c16 * 64 + ((g ^ (c16 & 7)) * 8) + (quad & 1) * 4] = pk;
    }

    // rescale O (alpha is a per-lane scalar)
#pragma unroll
    for (int n = 0; n < 8; ++n)
#pragma unroll
      for (int r = 0; r < 4; ++r) Ot[n][r] *= alpha;

    __asm__ volatile("s_waitcnt lgkmcnt(0)" ::: "memory");  // P writes -> P reads (same wave)

    // O^T += V^T P^T : A=V^T[d][k] frags, B=P^T (= rows of Pl[q][k])
    {
      f16x8 pf0 = *(const f16x8*)&Pl[wv][c16 * 64 + swp];
      f16x8 pf1 = *(const f16x8*)&Pl[wv][c16 * 64 + swp1];
#pragma unroll
      for (int n = 0; n < 8; ++n) {
        int rowv = (n * 16 + c16) * 64;
        f16x8 vf0 = *(const f16x8*)&Vl[rowv + swp];
        Ot[n] = __builtin_amdgcn_mfma_f32_16x16x32_f16(vf0, pf0, Ot[n], 0, 0, 0);
        f16x8 vf1 = *(const f16x8*)&Vl[rowv + swp1];
        Ot[n] = __builtin_amdgcn_mfma_f32_16x16x32_f16(vf1, pf1, Ot[n], 0, 0, 0);
      }
    }
    __syncthreads();
  }

  // epilogue: O = O^T normalized; lane writes 4 contiguous d per tile (8B stores)
  float inv = 1.0f / l_run;
  size_t token = (size_t)(bb * 2048 + qt * 64 + wv * 16 + c16);
#pragma unroll
  for (int n = 0; n < 8; ++n) {
    f16x4 o;
#pragma unroll
    for (int r = 0; r < 4; ++r) o[r] = (f16)(Ot[n][r] * inv);
    *(f16x4*)&ao[token * 4096 + h * 128 + n * 16 + quad * 4] = o;
  }
}

// ---------------- output projection: out = ao @ wo^T (fp32 out) ----------------
__global__ __launch_bounds__(512, 2) void gemm_out(
    const f16* __restrict__ ao, const f16* __restrict__ woh, float* __restrict__ out) {
  __shared__ __align__(16) f16 lds[73728];
  const int id = blockIdx.x;
  const int swz = (id & 7) * 64 + (id >> 3);  // 512 = 8 XCD * 64 (bijective)
  const int bx = swz % 32, by = swz / 32;
  f32x4 acc[4][4];
  gemm_core256(ao + (size_t)by * 256 * 4096, woh + (size_t)bx * 128 * 4096, lds, acc);
  const int tid = threadIdx.x, ln = tid & 63, wv = tid >> 6;
  const int wr = wv >> 1, wc = wv & 1;
  const int c16 = ln & 15, quad = ln >> 4;
#pragma unroll
  for (int mi = 0; mi < 4; ++mi)
#pragma unroll
    for (int ni = 0; ni < 4; ++ni) {
      int n = bx * 128 + wc * 64 + ni * 16 + c16;
      int m0 = by * 256 + wr * 64 + mi * 16 + quad * 4;
#pragma unroll
      for (int r = 0; r < 4; ++r)
        out[(size_t)(m0 + r) * 4096 + n] = acc[mi][ni][r];
    }
}

// ---------------- launch ----------------
extern "C" void kernel_launch(void* const* d_in, const int* in_sizes, int n_in,
                              void* d_out, int out_size, void* d_ws, size_t ws_size,
                              hipStream_t stream) {
  const float* x  = (const float*)d_in[0];
  const float* wq = (const float*)d_in[1];
  const float* wk = (const float*)d_in[2];
  const float* wv = (const float*)d_in[3];
  const float* wo = (const float*)d_in[4];
  const float* fc = (const float*)d_in[5];
  const float* fs = (const float*)d_in[6];
  float* out = (float*)d_out;

  char* ws = (char*)d_ws;
  f16* xh  = (f16*)(ws + 0);          // 32 MiB  x fp16 [4096][4096]
  f16* wqh = (f16*)(ws + 33554432);   // 32 MiB
  f16* wkh = (f16*)(ws + 67108864);   // 8 MiB
  f16* wvh = (f16*)(ws + 75497472);   // 8 MiB
  f16* woh = (f16*)(ws + 83886080);   // 32 MiB
  f16* qh  = (f16*)(ws + 117440512);  // 32 MiB  Q [4096][4096]
  f16* kh  = (f16*)(ws + 150994944);  // 8 MiB   K [4096][1024]
  f16* vt  = (f16*)(ws + 159383552);  // 8 MiB   V^T [2][8][128][2048]
  f16* ao  = (f16*)(ws + 167772160);  // 32 MiB  attn out [4096][4096]

  cast_all<<<57344, 256, 0, stream>>>(x, wq, wk, wv, wo, xh, wqh, wkh, wvh, woh);
  gemm_qkv<<<768, 512, 0, stream>>>(xh, wqh, wkh, wvh, qh, kh, vt);
  rope_qk<<<10240, 256, 0, stream>>>(qh, kh, fc, fs);
  attn<<<dim3(32, 32, 2), 256, 0, stream>>>(qh, kh, vt, ao);
  gemm_out<<<512, 512, 0, stream>>>(ao, woh, out);
}